// Round 8
// baseline (9522.392 us; speedup 1.0000x reference)
//
#include <hip/hip_runtime.h>

typedef unsigned short u16;
typedef unsigned int u32;
typedef unsigned long long u64;
typedef __attribute__((ext_vector_type(8))) short bf16x8;   // 8 bf16 = 4 VGPRs
typedef __attribute__((ext_vector_type(4))) float f32x4;
typedef __attribute__((ext_vector_type(4))) u32 u32x4;

namespace {
constexpr int kT = 1024, kI = 64, kH = 512, kO = 24;
constexpr int kBH = 64 * kH;                  // 32768 elems per h buffer (bf16)
constexpr int kNWG = 50;                      // 16 L1 + 32 L2 + 2 OUT
// h1: 4 bufs @0, h2: 4 bufs after (k mod 4), tags k mod 3, buf3 invalid-init
constexpr unsigned kBarOff = 8u * (unsigned)kBH * 2u;   // 524288 B
// ctl ints: [0..63] flagL2[ub2*4+g], [64..67] flagOUT[g]  (g = group 0..3)
}

__device__ __forceinline__ u16 f2bf(float f) {   // round-to-nearest-even
  union { float f; u32 u; } c; c.f = f;
  u32 u = c.u + 0x7FFFu + ((c.u >> 16) & 1u);
  return (u16)(u >> 16);
}
__device__ __forceinline__ float sigf(float x) { return 1.0f / (1.0f + __expf(-x)); }
__device__ __forceinline__ float tanhf_(float x) {
  float e = __expf(2.0f * x); return 1.0f - 2.0f / (e + 1.0f);  // safe at +-inf
}
__device__ __forceinline__ bf16x8 cvt8(const float* p) {  // fp32x8 -> bf16x8 (RNE)
  const float4 f0 = *reinterpret_cast<const float4*>(p);
  const float4 f1 = *reinterpret_cast<const float4*>(p + 4);
  bf16x8 r;
  r[0] = (short)f2bf(f0.x); r[1] = (short)f2bf(f0.y);
  r[2] = (short)f2bf(f0.z); r[3] = (short)f2bf(f0.w);
  r[4] = (short)f2bf(f1.x); r[5] = (short)f2bf(f1.y);
  r[6] = (short)f2bf(f1.z); r[7] = (short)f2bf(f1.w);
  return r;
}
__device__ __forceinline__ f32x4 mfma(bf16x8 a, bf16x8 b, f32x4 c) {
  return __builtin_amdgcn_mfma_f32_16x16x32_bf16(a, b, c, 0, 0, 0);
}
__device__ __forceinline__ int ldflag(const int* s, int i) {
  return __hip_atomic_load(&s[i], __ATOMIC_RELAXED, __HIP_MEMORY_SCOPE_AGENT);
}
__device__ __forceinline__ void stflag(int* s, int i, int v) {
  __hip_atomic_store(&s[i], v, __ATOMIC_RELAXED, __HIP_MEMORY_SCOPE_AGENT);
}
// PIPELINED agent fetch (R5-proven): all loads in one asm block, sc0 sc1
// (bypass L1+L2, coherent), ONE vmcnt drain => ~1 round trip per handshake.
union V16 { u32x4 u; bf16x8 v; };
__device__ __forceinline__ void fetch4(const u16* p, bf16x8* ch) {
  u32x4 a, b, c, d;
  asm volatile(
    "global_load_dwordx4 %0, %4, off sc0 sc1\n\t"
    "global_load_dwordx4 %1, %4, off offset:64 sc0 sc1\n\t"
    "global_load_dwordx4 %2, %4, off offset:128 sc0 sc1\n\t"
    "global_load_dwordx4 %3, %4, off offset:192 sc0 sc1\n\t"
    "s_waitcnt vmcnt(0)"
    : "=&v"(a), "=&v"(b), "=&v"(c), "=&v"(d) : "v"(p) : "memory");
  V16 t;
  t.u = a; ch[0] = t.v;  t.u = b; ch[1] = t.v;
  t.u = c; ch[2] = t.v;  t.u = d; ch[3] = t.v;
}
__device__ __forceinline__ void fetch8(const u16* p, bf16x8* ch) {
  u32x4 a, b, c, d, e, f, g2, h;
  asm volatile(
    "global_load_dwordx4 %0, %8, off sc0 sc1\n\t"
    "global_load_dwordx4 %1, %8, off offset:64 sc0 sc1\n\t"
    "global_load_dwordx4 %2, %8, off offset:128 sc0 sc1\n\t"
    "global_load_dwordx4 %3, %8, off offset:192 sc0 sc1\n\t"
    "global_load_dwordx4 %4, %8, off offset:256 sc0 sc1\n\t"
    "global_load_dwordx4 %5, %8, off offset:320 sc0 sc1\n\t"
    "global_load_dwordx4 %6, %8, off offset:384 sc0 sc1\n\t"
    "global_load_dwordx4 %7, %8, off offset:448 sc0 sc1\n\t"
    "s_waitcnt vmcnt(0)"
    : "=&v"(a), "=&v"(b), "=&v"(c), "=&v"(d),
      "=&v"(e), "=&v"(f), "=&v"(g2), "=&v"(h) : "v"(p) : "memory");
  V16 t;
  t.u = a; ch[0] = t.v;  t.u = b;  ch[1] = t.v;
  t.u = c; ch[2] = t.v;  t.u = d;  ch[3] = t.v;
  t.u = e; ch[4] = t.v;  t.u = f;  ch[5] = t.v;
  t.u = g2; ch[6] = t.v; t.u = h;  ch[7] = t.v;
}
// tick tag (k mod 3) in LSBs of bf16 elems 0,1 of each 8B granule.
// (buf = k mod 4, tag = k mod 3) repeat together every 12 ticks; distance-4
// throttle caps skew at 4 => no aliasing. (1,1) tag = INVALID buf3 init.
__device__ __forceinline__ u32 pat3(int t3) {
  return ((u32)t3 & 1u) | ((((u32)t3 >> 1) & 1u) << 16);
}
template<int N>
__device__ __forceinline__ bool tagsok(const bf16x8* ch, u32 pat) {
  bool ok = true;
#pragma unroll
  for (int c = 0; c < N; ++c) {
    union { bf16x8 v; u32 u[4]; } t; t.v = ch[c];
    ok = ok && ((t.u[0] & 0x10001u) == pat) && ((t.u[2] & 0x10001u) == pat);
  }
  return ok;
}
// tagged-data wait: phase 1 polls each lane's first 8B granule (cheap),
// phase 2 pipelined fetch + full tag verify (~1 iter). With 2-stream
// interleave the data is ~1 iteration old => phase 1 usually hits at once.
template<int N>
__device__ __forceinline__ void dataD(const u16* p, u32 pat, bf16x8* ch) {
  int spins = 0;
  for (;;) {
    u64 g0 = __hip_atomic_load((const u64*)p, __ATOMIC_RELAXED, __HIP_MEMORY_SCOPE_AGENT);
    if (__all(((u32)g0 & 0x10001u) == pat)) break;
    if ((++spins & 3) == 3) __builtin_amdgcn_s_sleep(1);
  }
  spins = 0;
  for (;;) {
    if constexpr (N == 4) fetch4(p, ch); else fetch8(p, ch);
    if (__all(tagsok<N>(ch, pat))) break;
    if ((++spins & 7) == 7) __builtin_amdgcn_s_sleep(1);
  }
  __asm__ volatile("" ::: "memory");
}
// tagged h store: 4 bf16 + 2 tag bits, ONE agent-scope atomic 8B store
__device__ __forceinline__ void st_h(u16* p, const float* h, int t3) {
  u16 a = (u16)((f2bf(h[0]) & ~1u) | ((u32)t3 & 1u));
  u16 b = (u16)((f2bf(h[1]) & ~1u) | (((u32)t3 >> 1) & 1u));
  u64 v = (u64)a | ((u64)b << 16) | ((u64)f2bf(h[2]) << 32) | ((u64)f2bf(h[3]) << 48);
  __hip_atomic_store((u64*)p, v, __ATOMIC_RELAXED, __HIP_MEMORY_SCOPE_AGENT);
}
// amortized producer throttle: consumers' flags >= k-3 (they fetch-verified
// tick k-3) before overwriting tick k-4 rows in the mod-4 ring (per group).
__device__ __forceinline__ void throttle(const int* f, int idx, bool act,
                                         int k, int& bound) {
  if (bound >= k - 3) return;
  for (;;) {
    int v = act ? ldflag(f, idx) : 0x7fffffff;
    if (__all(v >= k - 3)) { bound = __all(v >= k) ? k : (k - 3); break; }
    __builtin_amdgcn_s_sleep(2);
  }
}

// 2-STREAM FAT-WG roles (50 WGs x 256 thr). Each WG serves TWO batch groups
// (streams s=0,1 -> group gp*2+s, 16 batches each) per loop iteration; each
// stream's tick-k inputs were stored a full iteration earlier, so the other
// stream's segment hides store-visibility + poll latency (R4 idea, viable
// now that R5's pipelined fetch removed the per-handshake serialized RTs).
//   wg  0..15 : L1. ub=wg>>1 (64-unit block), gp=wg&1. 4 waves = K-quarters;
//               x-GEMM (K=64) on kh1/kh2, n-gate x-partial via LDS redx.
//   wg 16..47 : L2. ub2=(wg-16)>>1 (32-unit block), gp. 4 waves = quarters
//               of combined K=1024: kh0,1 = wih2@h1[k]; kh2,3 = whh2@h2[k-1].
//   wg 48..49 : OUT. gp. 4 waves = mat x K-half. fin=mat0,kh0.
// Segment body == R7's proven tick body (2 barriers, LDS exchange).
// flagL2[ub2*4+g]/flagOUT[g] post after segment's 1st barrier (fetch-verified).
// MFMA 16x16x32: A=weights m=unit(l15), B=h n=batch(l15), C/D col=l15(batch),
// row=q*4+r(unit) -> activations lane-local.
__global__ __launch_bounds__(256, 1) void stackgru(
    const float* __restrict__ x,
    const float* __restrict__ wih1, const float* __restrict__ whh1,
    const float* __restrict__ bih1, const float* __restrict__ bhh1,
    const float* __restrict__ wih2, const float* __restrict__ whh2,
    const float* __restrict__ bih2, const float* __restrict__ bhh2,
    const float* __restrict__ wo1, const float* __restrict__ bo1,
    const float* __restrict__ wo2, const float* __restrict__ bo2,
    float* __restrict__ out, u16* __restrict__ hbuf, int* __restrict__ ctl)
{
  __shared__ float red[3][3][4][64][4];   // 36 KB: [slot][gate][m][lane][r]
  __shared__ float redx[2][4][64][4];     // 8 KB: x n-gate partials (L1)
  __shared__ float sbias[4][64];          // staged biases
  const int wg = blockIdx.x;
  const int tid = threadIdx.x;
  const int lane = tid & 63;
  const int w = tid >> 6;                 // wave 0..3
  const int l15 = lane & 15;
  const int q = lane >> 4;

  u16* h1b = hbuf;                        // 4 * kBH
  u16* h2b = hbuf + 4 * kBH;              // 4 * kBH

  if (wg < 16) {
    // ---------------- layer 1 ----------------
    const int ub = wg >> 1, gp = wg & 1;
    const int U0 = ub * 64;
    const int kh = w;                     // K-quarter (0..3), 128 K each
    bf16x8 whf[3][4][4];                  // 192 VGPR resident w_hh1
#pragma unroll
    for (int gg = 0; gg < 3; ++gg)
#pragma unroll
      for (int m = 0; m < 4; ++m)
#pragma unroll
        for (int c = 0; c < 4; ++c)
          whf[gg][m][c] = cvt8(whh1 + (size_t)(gg * kH + U0 + m * 16 + l15) * kH
                               + (kh * 4 + c) * 32 + q * 8);
    const bool hasx = (kh == 1 || kh == 2);
    const int xch = kh - 1;               // x chunk 0/1 (K=64 total)
    bf16x8 aihf[3][4];                    // 48 VGPR (kh1/kh2 only)
    if (hasx)
#pragma unroll
      for (int gg = 0; gg < 3; ++gg)
#pragma unroll
        for (int m = 0; m < 4; ++m)
          aihf[gg][m] = cvt8(wih1 + (size_t)(gg * kH + U0 + m * 16 + l15) * kI
                             + xch * 32 + q * 8);
    if (tid < 64) {                       // stage biases once
      int u = U0 + tid;
      sbias[0][tid] = bih1[u]          + bhh1[u];
      sbias[1][tid] = bih1[kH + u]     + bhh1[kH + u];
      sbias[2][tid] = bih1[2 * kH + u];
      sbias[3][tid] = bhh1[2 * kH + u];
    }
    float h1l[2][4][4];                   // fp32 master h1 per stream (kh0)
#pragma unroll
    for (int s = 0; s < 2; ++s)
#pragma unroll
      for (int m = 0; m < 4; ++m)
#pragma unroll
        for (int r = 0; r < 4; ++r) h1l[s][m][r] = 0.0f;
    int bnd[2] = {0, 0};
    __syncthreads();
    for (int k = 1; k <= kT; ++k) {
      const int t3 = k % 3, t3p = (k - 1) % 3;
#pragma unroll
      for (int s = 0; s < 2; ++s) {
        const int g = gp * 2 + s;
        const int bb = g * 16 + l15;
        // throttle watch (kh0): lanes 0..15 flagL2 of g, lane 16 flagOUT[g]
        const int thridx = (lane < 16) ? (lane * 4 + g) : (64 + g);
        const bool thract = (lane < 17);
        bf16x8 xf;
        if (hasx)
          xf = cvt8(x + ((size_t)bb * kT + (k - 1)) * kI + xch * 32 + q * 8);
        bf16x8 ch[4];
        dataD<4>(h1b + ((k - 1) & 3) * kBH + (size_t)bb * kH + kh * 128 + q * 8,
                 pat3(t3p), ch);
        f32x4 aR[4], aZ[4], aN[4];
#pragma unroll
        for (int m = 0; m < 4; ++m) { aR[m] = {0,0,0,0}; aZ[m] = {0,0,0,0}; aN[m] = {0,0,0,0}; }
#pragma unroll
        for (int m = 0; m < 4; ++m)
#pragma unroll
          for (int c = 0; c < 4; ++c) {
            aR[m] = mfma(whf[0][m][c], ch[c], aR[m]);
            aZ[m] = mfma(whf[1][m][c], ch[c], aZ[m]);
            aN[m] = mfma(whf[2][m][c], ch[c], aN[m]);
          }
        if (hasx) {
          f32x4 xN[4];
#pragma unroll
          for (int m = 0; m < 4; ++m) xN[m] = {0,0,0,0};
#pragma unroll
          for (int m = 0; m < 4; ++m) {
            aR[m] = mfma(aihf[0][m], xf, aR[m]);   // r,z: fold x into h-accum
            aZ[m] = mfma(aihf[1][m], xf, aZ[m]);
            xN[m] = mfma(aihf[2][m], xf, xN[m]);   // n_i must stay separate
          }
#pragma unroll
          for (int m = 0; m < 4; ++m)
#pragma unroll
            for (int r = 0; r < 4; ++r) redx[xch][m][lane][r] = xN[m][r];
        }
        if (kh != 0) {
#pragma unroll
          for (int m = 0; m < 4; ++m)
#pragma unroll
            for (int r = 0; r < 4; ++r) {
              red[kh - 1][0][m][lane][r] = aR[m][r];
              red[kh - 1][1][m][lane][r] = aZ[m][r];
              red[kh - 1][2][m][lane][r] = aN[m][r];
            }
        } else {
          throttle(ctl, thridx, thract, k, bnd[s]);   // h1 anti-dep (group g)
        }
        __syncthreads();
        if (kh == 0) {
#pragma unroll
          for (int m = 0; m < 4; ++m) {
            float hnew[4];
#pragma unroll
            for (int r = 0; r < 4; ++r) {
              float sR = aR[m][r] + red[0][0][m][lane][r] + red[1][0][m][lane][r] + red[2][0][m][lane][r];
              float sZ = aZ[m][r] + red[0][1][m][lane][r] + red[1][1][m][lane][r] + red[2][1][m][lane][r];
              float sN = aN[m][r] + red[0][2][m][lane][r] + red[1][2][m][lane][r] + red[2][2][m][lane][r];
              float sNi = redx[0][m][lane][r] + redx[1][m][lane][r];
              int uu = m * 16 + q * 4 + r;
              float rr = sigf(sR + sbias[0][uu]);
              float zz = sigf(sZ + sbias[1][uu]);
              float nn = tanhf_(sNi + sbias[2][uu] + rr * (sN + sbias[3][uu]));
              float h  = (1.0f - zz) * nn + zz * h1l[s][m][r];
              h1l[s][m][r] = h; hnew[r] = h;
            }
            st_h(h1b + (k & 3) * kBH + (size_t)bb * kH + U0 + m * 16 + q * 4, hnew, t3);
          }
        }
        __syncthreads();                  // guards red/redx reuse
      }
    }
  } else if (wg < 48) {
    // ---------------- layer 2 (combined K=1024 GEMM) ----------------
    const int j2 = wg - 16;
    const int ub2 = j2 >> 1, gp = j2 & 1;
    const int U0 = ub2 * 32;
    const int kh = w;                     // 0,1: wih2 halves; 2,3: whh2 halves
    const float* src = (kh < 2) ? wih2 : whh2;
    const int koff = (kh & 1) * 256;      // K-offset within the 512-dim matrix
    bf16x8 whf[3][2][8];                  // 192 VGPR resident weights
#pragma unroll
    for (int gg = 0; gg < 3; ++gg)
#pragma unroll
      for (int m = 0; m < 2; ++m)
#pragma unroll
        for (int c = 0; c < 8; ++c)
          whf[gg][m][c] = cvt8(src + (size_t)(gg * kH + U0 + m * 16 + l15) * kH
                               + koff + c * 32 + q * 8);
    if (tid < 32) {                       // stage biases once
      int u = U0 + tid;
      sbias[0][tid] = bih2[u]          + bhh2[u];
      sbias[1][tid] = bih2[kH + u]     + bhh2[kH + u];
      sbias[2][tid] = bih2[2 * kH + u];
      sbias[3][tid] = bhh2[2 * kH + u];
    }
    float h2l[2][2][4];                   // fp32 master h2 per stream (kh0)
#pragma unroll
    for (int s = 0; s < 2; ++s)
#pragma unroll
      for (int m = 0; m < 2; ++m)
#pragma unroll
        for (int r = 0; r < 4; ++r) h2l[s][m][r] = 0.0f;
    int bnd[2] = {0, 0};
    __syncthreads();
    const bool upd = (kh == 0);
    for (int k = 1; k <= kT; ++k) {
      const int t3 = k % 3, t3p = (k - 1) % 3;
#pragma unroll
      for (int s = 0; s < 2; ++s) {
        const int g = gp * 2 + s;
        const int bb = g * 16 + l15;
        const u16* base; u32 pat;
        if (kh < 2) { base = h1b + (k & 3) * kBH;       pat = pat3(t3);  }
        else        { base = h2b + ((k - 1) & 3) * kBH; pat = pat3(t3p); }
        bf16x8 ch[8];
        dataD<8>(base + (size_t)bb * kH + koff + q * 8, pat, ch);
        f32x4 a[3][2];
#pragma unroll
        for (int gg = 0; gg < 3; ++gg)
#pragma unroll
          for (int m = 0; m < 2; ++m) a[gg][m] = {0,0,0,0};
#pragma unroll
        for (int m = 0; m < 2; ++m)
#pragma unroll
          for (int c = 0; c < 8; ++c) {
            a[0][m] = mfma(whf[0][m][c], ch[c], a[0][m]);
            a[1][m] = mfma(whf[1][m][c], ch[c], a[1][m]);
            a[2][m] = mfma(whf[2][m][c], ch[c], a[2][m]);
          }
        if (kh != 0) {
          const int sl = kh - 1;          // kh1 -> gi-half2, kh2/3 -> gh halves
#pragma unroll
          for (int gg = 0; gg < 3; ++gg)
#pragma unroll
            for (int m = 0; m < 2; ++m)
#pragma unroll
              for (int r = 0; r < 4; ++r) red[sl][gg][m][lane][r] = a[gg][m][r];
        } else {
          throttle(ctl, 64 + g, lane < 1, k, bnd[s]);   // h2 anti-dep (OUT)
        }
        __syncthreads();
        if (tid == 0) stflag(ctl, ub2 * 4 + g, k);  // fetch-verified tick k
        if (upd) {
#pragma unroll
          for (int m = 0; m < 2; ++m) {
            float hnew[4];
#pragma unroll
            for (int r = 0; r < 4; ++r) {
              float gi0 = a[0][m][r] + red[0][0][m][lane][r];
              float gi1 = a[1][m][r] + red[0][1][m][lane][r];
              float gi2 = a[2][m][r] + red[0][2][m][lane][r];
              float gh0 = red[1][0][m][lane][r] + red[2][0][m][lane][r];
              float gh1 = red[1][1][m][lane][r] + red[2][1][m][lane][r];
              float gh2 = red[1][2][m][lane][r] + red[2][2][m][lane][r];
              int uu = m * 16 + q * 4 + r;
              float rr = sigf(gi0 + gh0 + sbias[0][uu]);
              float zz = sigf(gi1 + gh1 + sbias[1][uu]);
              float nn = tanhf_(gi2 + sbias[2][uu] + rr * (gh2 + sbias[3][uu]));
              float h  = (1.0f - zz) * nn + zz * h2l[s][m][r];
              h2l[s][m][r] = h; hnew[r] = h;
            }
            st_h(h2b + (k & 3) * kBH + (size_t)bb * kH + U0 + m * 16 + q * 4, hnew, t3);
          }
        }
        __syncthreads();                  // guards red reuse
      }
    }
  } else {
    // ---------------- output head ----------------
    const int gp = wg - 48;
    const int mat = w & 1, khh = w >> 1;  // matrix x K-half
    const float* wsel = mat ? wo2 : wo1;
    bf16x8 zf = {0,0,0,0,0,0,0,0};
    bf16x8 wof[2][8];
#pragma unroll
    for (int t = 0; t < 2; ++t)
#pragma unroll
      for (int c = 0; c < 8; ++c) {
        int row = t * 16 + l15;
        wof[t][c] = (row < kO) ? cvt8(wsel + (size_t)row * kH + khh * 256 + c * 32 + q * 8) : zf;
      }
    float bv1[2][4], bv2[2][4];
#pragma unroll
    for (int t = 0; t < 2; ++t)
#pragma unroll
      for (int r = 0; r < 4; ++r) {
        int o = t * 16 + q * 4 + r;
        bv1[t][r] = (o < kO) ? bo1[o] : 0.0f;
        bv2[t][r] = (o < kO) ? bo2[o] : 0.0f;
      }
    const bool fin = (mat == 0 && khh == 0);
    const u16* slab = mat ? h2b : h1b;
    for (int k = 1; k <= kT; ++k) {
      const u32 pat = pat3(k % 3);
#pragma unroll
      for (int s = 0; s < 2; ++s) {
        const int g = gp * 2 + s;
        const int bb = g * 16 + l15;
        bf16x8 ch[8];
        dataD<8>(slab + (k & 3) * kBH + (size_t)bb * kH + khh * 256 + q * 8, pat, ch);
        f32x4 a0 = {0,0,0,0}, a1 = {0,0,0,0};
#pragma unroll
        for (int c = 0; c < 8; ++c) {
          a0 = mfma(wof[0][c], ch[c], a0);
          a1 = mfma(wof[1][c], ch[c], a1);
        }
        if (!fin) {
          const int sl = mat * 2 + khh - 1;  // (0,1)->0 (1,0)->1 (1,1)->2
#pragma unroll
          for (int r = 0; r < 4; ++r) {
            red[sl][0][0][lane][r] = a0[r];
            red[sl][0][1][lane][r] = a1[r];
          }
        }
        __syncthreads();
        if (tid == 0) stflag(ctl, 64 + g, k);   // h1[k] & h2[k] fetch-verified
        if (fin) {
#pragma unroll
          for (int t = 0; t < 2; ++t) {
            int o0 = t * 16 + q * 4;
            if (o0 < kO) {
              f32x4 av = (t == 0) ? a0 : a1;
              float4 ov;
              ov.x = tanhf_(av[0] + red[0][0][t][lane][0] + bv1[t][0]) +
                     tanhf_(red[1][0][t][lane][0] + red[2][0][t][lane][0] + bv2[t][0]);
              ov.y = tanhf_(av[1] + red[0][0][t][lane][1] + bv1[t][1]) +
                     tanhf_(red[1][0][t][lane][1] + red[2][0][t][lane][1] + bv2[t][1]);
              ov.z = tanhf_(av[2] + red[0][0][t][lane][2] + bv1[t][2]) +
                     tanhf_(red[1][0][t][lane][2] + red[2][0][t][lane][2] + bv2[t][2]);
              ov.w = tanhf_(av[3] + red[0][0][t][lane][3] + bv1[t][3]) +
                     tanhf_(red[1][0][t][lane][3] + red[2][0][t][lane][3] + bv2[t][3]);
              *reinterpret_cast<float4*>(out + ((size_t)bb * kT + (k - 1)) * kO + o0) = ov;
            }
          }
        }
        __syncthreads();                  // guards red reuse
      }
    }
  }
}

extern "C" void kernel_launch(void* const* d_in, const int* in_sizes, int n_in,
                              void* d_out, int out_size, void* d_ws, size_t ws_size,
                              hipStream_t stream) {
  (void)in_sizes; (void)n_in; (void)out_size; (void)ws_size;
  // zero h buffers + control page; invalid-tag init for buf 3 of h1 & h2
  hipMemsetAsync(d_ws, 0, kBarOff + 1024, stream);
  hipMemsetAsync((char*)d_ws + 3u * kBH * 2u, 0x01, kBH * 2u, stream);  // h1 buf3
  hipMemsetAsync((char*)d_ws + 7u * kBH * 2u, 0x01, kBH * 2u, stream);  // h2 buf3
  const float* x    = (const float*)d_in[0];
  const float* wih1 = (const float*)d_in[1];
  const float* whh1 = (const float*)d_in[2];
  const float* bih1 = (const float*)d_in[3];
  const float* bhh1 = (const float*)d_in[4];
  const float* wih2 = (const float*)d_in[5];
  const float* whh2 = (const float*)d_in[6];
  const float* bih2 = (const float*)d_in[7];
  const float* bhh2 = (const float*)d_in[8];
  const float* wo1  = (const float*)d_in[9];
  const float* bo1  = (const float*)d_in[10];
  const float* wo2  = (const float*)d_in[11];
  const float* bo2  = (const float*)d_in[12];
  float* out  = (float*)d_out;
  u16* hbuf   = (u16*)d_ws;
  int* ctl    = (int*)((char*)d_ws + kBarOff);
  stackgru<<<dim3(kNWG), dim3(256), 0, stream>>>(
      x, wih1, whh1, bih1, bhh1, wih2, whh2, bih2, bhh2,
      wo1, bo1, wo2, bo2, out, hbuf, ctl);
}

// Round 9
// 5187.123 us; speedup vs baseline: 1.8358x; 1.8358x over previous
//
#include <hip/hip_runtime.h>

typedef unsigned short u16;
typedef unsigned int u32;
typedef unsigned long long u64;
typedef __attribute__((ext_vector_type(8))) short bf16x8;   // 8 bf16 = 4 VGPRs
typedef __attribute__((ext_vector_type(4))) float f32x4;
typedef __attribute__((ext_vector_type(4))) u32 u32x4;

namespace {
constexpr int kT = 1024, kI = 64, kH = 512, kO = 24;
constexpr int kBH = 64 * kH;                  // 32768 elems per h buffer (bf16)
constexpr int kNWG = 100;                     // 32 L1 + 64 L2 + 4 OUT
// h1: 4 bufs @0, h2: 4 bufs after (k mod 4), tags k mod 3, buf3 invalid-init
constexpr unsigned kBarOff = 8u * (unsigned)kBH * 2u;   // 524288 B
// ctl ints: [0..63] flagL2[j2] (j2 = ub2*4+g), [64..67] flagOUT[g]
}

__device__ __forceinline__ u16 f2bf(float f) {   // round-to-nearest-even
  union { float f; u32 u; } c; c.f = f;
  u32 u = c.u + 0x7FFFu + ((c.u >> 16) & 1u);
  return (u16)(u >> 16);
}
__device__ __forceinline__ float sigf(float x) { return 1.0f / (1.0f + __expf(-x)); }
__device__ __forceinline__ float tanhf_(float x) {
  float e = __expf(2.0f * x); return 1.0f - 2.0f / (e + 1.0f);  // safe at +-inf
}
__device__ __forceinline__ bf16x8 cvt8(const float* p) {  // fp32x8 -> bf16x8 (RNE)
  const float4 f0 = *reinterpret_cast<const float4*>(p);
  const float4 f1 = *reinterpret_cast<const float4*>(p + 4);
  bf16x8 r;
  r[0] = (short)f2bf(f0.x); r[1] = (short)f2bf(f0.y);
  r[2] = (short)f2bf(f0.z); r[3] = (short)f2bf(f0.w);
  r[4] = (short)f2bf(f1.x); r[5] = (short)f2bf(f1.y);
  r[6] = (short)f2bf(f1.z); r[7] = (short)f2bf(f1.w);
  return r;
}
__device__ __forceinline__ f32x4 mfma(bf16x8 a, bf16x8 b, f32x4 c) {
  return __builtin_amdgcn_mfma_f32_16x16x32_bf16(a, b, c, 0, 0, 0);
}
__device__ __forceinline__ int ldflag(const int* s, int i) {
  return __hip_atomic_load(&s[i], __ATOMIC_RELAXED, __HIP_MEMORY_SCOPE_AGENT);
}
__device__ __forceinline__ void stflag(int* s, int i, int v) {
  __hip_atomic_store(&s[i], v, __ATOMIC_RELAXED, __HIP_MEMORY_SCOPE_AGENT);
}
// LDS-ONLY barrier (R8 post-mortem fix): __syncthreads drains vmcnt(0),
// serializing a ~1us store-ack RT into every tick. Our barriers only guard
// LDS (red/redx) reuse -- global h stores are tag-protected fire-and-forget.
// s_waitcnt lgkmcnt(0) orders the ds_writes; raw s_barrier skips the drain.
__device__ __forceinline__ void barrier_lds() {
  asm volatile("s_waitcnt lgkmcnt(0)" ::: "memory");
  __builtin_amdgcn_s_barrier();
}
// PIPELINED agent fetch (R5-proven): all loads in one asm block, sc0 sc1
// (bypass L1+L2, coherent), ONE vmcnt drain => ~1 round trip per handshake.
// NOTE: the vmcnt(0) also waits for this wave's own outstanding stores
// (fire-and-forget st_h from the previous tick) -- those acks overlap the
// load RT rather than serializing before it.
union V16 { u32x4 u; bf16x8 v; };
__device__ __forceinline__ void fetch4(const u16* p, bf16x8* ch) {
  u32x4 a, b, c, d;
  asm volatile(
    "global_load_dwordx4 %0, %4, off sc0 sc1\n\t"
    "global_load_dwordx4 %1, %4, off offset:64 sc0 sc1\n\t"
    "global_load_dwordx4 %2, %4, off offset:128 sc0 sc1\n\t"
    "global_load_dwordx4 %3, %4, off offset:192 sc0 sc1\n\t"
    "s_waitcnt vmcnt(0)"
    : "=&v"(a), "=&v"(b), "=&v"(c), "=&v"(d) : "v"(p) : "memory");
  V16 t;
  t.u = a; ch[0] = t.v;  t.u = b; ch[1] = t.v;
  t.u = c; ch[2] = t.v;  t.u = d; ch[3] = t.v;
}
__device__ __forceinline__ void fetch8(const u16* p, bf16x8* ch) {
  u32x4 a, b, c, d, e, f, g2, h;
  asm volatile(
    "global_load_dwordx4 %0, %8, off sc0 sc1\n\t"
    "global_load_dwordx4 %1, %8, off offset:64 sc0 sc1\n\t"
    "global_load_dwordx4 %2, %8, off offset:128 sc0 sc1\n\t"
    "global_load_dwordx4 %3, %8, off offset:192 sc0 sc1\n\t"
    "global_load_dwordx4 %4, %8, off offset:256 sc0 sc1\n\t"
    "global_load_dwordx4 %5, %8, off offset:320 sc0 sc1\n\t"
    "global_load_dwordx4 %6, %8, off offset:384 sc0 sc1\n\t"
    "global_load_dwordx4 %7, %8, off offset:448 sc0 sc1\n\t"
    "s_waitcnt vmcnt(0)"
    : "=&v"(a), "=&v"(b), "=&v"(c), "=&v"(d),
      "=&v"(e), "=&v"(f), "=&v"(g2), "=&v"(h) : "v"(p) : "memory");
  V16 t;
  t.u = a; ch[0] = t.v;  t.u = b;  ch[1] = t.v;
  t.u = c; ch[2] = t.v;  t.u = d;  ch[3] = t.v;
  t.u = e; ch[4] = t.v;  t.u = f;  ch[5] = t.v;
  t.u = g2; ch[6] = t.v; t.u = h;  ch[7] = t.v;
}
// tick tag (k mod 3) in LSBs of bf16 elems 0,1 of each 8B granule.
// (buf = k mod 4, tag = k mod 3) repeat together every 12 ticks; distance-4
// throttle caps skew at 4 => no aliasing. (1,1) tag = INVALID buf3 init.
__device__ __forceinline__ u32 pat3(int t3) {
  return ((u32)t3 & 1u) | ((((u32)t3 >> 1) & 1u) << 16);
}
template<int N>
__device__ __forceinline__ bool tagsok(const bf16x8* ch, u32 pat) {
  bool ok = true;
#pragma unroll
  for (int c = 0; c < N; ++c) {
    union { bf16x8 v; u32 u[4]; } t; t.v = ch[c];
    ok = ok && ((t.u[0] & 0x10001u) == pat) && ((t.u[2] & 0x10001u) == pat);
  }
  return ok;
}
// OPTIMISTIC tagged-data wait (R8 post-mortem fix): issue the pipelined
// fetch FIRST and verify -- 1 RT total when data is ready (steady state for
// recurrence reads; R4/R8 proved readiness). Only on miss fall back to the
// cheap 8B-granule poll (R7's congestion-safe loop), then refetch.
template<int N>
__device__ __forceinline__ void dataD(const u16* p, u32 pat, bf16x8* ch) {
  if constexpr (N == 4) fetch4(p, ch); else fetch8(p, ch);
  if (__all(tagsok<N>(ch, pat))) { __asm__ volatile("" ::: "memory"); return; }
  int spins = 0;
  for (;;) {
    u64 g0 = __hip_atomic_load((const u64*)p, __ATOMIC_RELAXED, __HIP_MEMORY_SCOPE_AGENT);
    if (__all(((u32)g0 & 0x10001u) == pat)) {
      if constexpr (N == 4) fetch4(p, ch); else fetch8(p, ch);
      if (__all(tagsok<N>(ch, pat))) break;
    }
    if ((++spins & 3) == 3) __builtin_amdgcn_s_sleep(1);
  }
  __asm__ volatile("" ::: "memory");
}
// tagged h store: 4 bf16 + 2 tag bits, ONE agent-scope atomic 8B store
__device__ __forceinline__ void st_h(u16* p, const float* h, int t3) {
  u16 a = (u16)((f2bf(h[0]) & ~1u) | ((u32)t3 & 1u));
  u16 b = (u16)((f2bf(h[1]) & ~1u) | (((u32)t3 >> 1) & 1u));
  u64 v = (u64)a | ((u64)b << 16) | ((u64)f2bf(h[2]) << 32) | ((u64)f2bf(h[3]) << 48);
  __hip_atomic_store((u64*)p, v, __ATOMIC_RELAXED, __HIP_MEMORY_SCOPE_AGENT);
}
// amortized producer throttle: consumers' flags >= k-3 (they fetch-verified
// tick k-3) before overwriting tick k-4 rows in the mod-4 ring.
__device__ __forceinline__ void throttle(const int* f, int idx, bool act,
                                         int k, int& bound) {
  if (bound >= k - 3) return;
  for (;;) {
    int v = act ? ldflag(f, idx) : 0x7fffffff;
    if (__all(v >= k - 3)) { bound = __all(v >= k) ? k : (k - 3); break; }
    __builtin_amdgcn_s_sleep(2);
  }
}

// FAT-WG roles (100 WGs x 256 thr; 4 batch-groups of 16) == R7 structure.
// R8 changes are LOCAL: optimistic fetch (poll RT removed when ready) and
// LDS-only barriers (vmcnt-drain RT removed). Critical recurrence chain:
// visibility||barrier + fetch-RT + MFMA + act ~= 3us/tick (was ~4.9).
//   wg  0..31 : L1. ub=wg>>2 (64-unit block), g=wg&3 (16-batch group).
//               4 waves = K-quarters. x-GEMM (K=64) on kh1/kh2, redx via LDS.
//   wg 32..95 : L2. ub2 (32-unit block), g. 4 waves = quarters of combined
//               K=1024: kh0,1 = wih2@h1[k]; kh2,3 = whh2@h2[k-1].
//   wg 96..99 : OUT. g3 group. 4 waves = mat x K-half. fin=mat0,kh0.
// flagL2[j2]/flagOUT[g] post after the first barrier (fetch-verified).
// MFMA 16x16x32: A=weights m=unit(l15), B=h n=batch(l15), C/D col=l15(batch),
// row=q*4+r(unit) -> activations lane-local.
__global__ __launch_bounds__(256, 1) void stackgru(
    const float* __restrict__ x,
    const float* __restrict__ wih1, const float* __restrict__ whh1,
    const float* __restrict__ bih1, const float* __restrict__ bhh1,
    const float* __restrict__ wih2, const float* __restrict__ whh2,
    const float* __restrict__ bih2, const float* __restrict__ bhh2,
    const float* __restrict__ wo1, const float* __restrict__ bo1,
    const float* __restrict__ wo2, const float* __restrict__ bo2,
    float* __restrict__ out, u16* __restrict__ hbuf, int* __restrict__ ctl)
{
  __shared__ float red[3][3][4][64][4];   // 36 KB: [slot][gate][m][lane][r]
  __shared__ float redx[2][4][64][4];     // 8 KB: x n-gate partials (L1)
  __shared__ float sbias[4][64];          // staged biases
  const int wg = blockIdx.x;
  const int tid = threadIdx.x;
  const int lane = tid & 63;
  const int w = tid >> 6;                 // wave 0..3
  const int l15 = lane & 15;
  const int q = lane >> 4;

  u16* h1b = hbuf;                        // 4 * kBH
  u16* h2b = hbuf + 4 * kBH;              // 4 * kBH

  if (wg < 32) {
    // ---------------- layer 1 ----------------
    const int ub = wg >> 2, g = wg & 3;
    const int U0 = ub * 64;
    const int bb = g * 16 + l15;
    const int kh = w;                     // K-quarter (0..3), 128 K each
    bf16x8 whf[3][4][4];                  // 192 VGPR resident w_hh1
#pragma unroll
    for (int gg = 0; gg < 3; ++gg)
#pragma unroll
      for (int m = 0; m < 4; ++m)
#pragma unroll
        for (int c = 0; c < 4; ++c)
          whf[gg][m][c] = cvt8(whh1 + (size_t)(gg * kH + U0 + m * 16 + l15) * kH
                               + (kh * 4 + c) * 32 + q * 8);
    const bool hasx = (kh == 1 || kh == 2);
    const int xch = kh - 1;               // x chunk 0/1 (K=64 total)
    bf16x8 aihf[3][4];                    // 48 VGPR (kh1/kh2 only)
    if (hasx)
#pragma unroll
      for (int gg = 0; gg < 3; ++gg)
#pragma unroll
        for (int m = 0; m < 4; ++m)
          aihf[gg][m] = cvt8(wih1 + (size_t)(gg * kH + U0 + m * 16 + l15) * kI
                             + xch * 32 + q * 8);
    if (tid < 64) {                       // stage biases once
      int u = U0 + tid;
      sbias[0][tid] = bih1[u]          + bhh1[u];
      sbias[1][tid] = bih1[kH + u]     + bhh1[kH + u];
      sbias[2][tid] = bih1[2 * kH + u];
      sbias[3][tid] = bhh1[2 * kH + u];
    }
    float h1l[4][4];                      // fp32 master h1 (kh0 wave)
#pragma unroll
    for (int m = 0; m < 4; ++m)
#pragma unroll
      for (int r = 0; r < 4; ++r) h1l[m][r] = 0.0f;
    __syncthreads();
    // throttle watch (kh0): lanes 0..15 = flagL2 of group, lane 16 = flagOUT
    const int thridx = (lane < 16) ? (lane * 4 + g) : (64 + g);
    const bool thract = (lane < 17);
    int bound = 0;
    for (int k = 1; k <= kT; ++k) {
      const int t3 = k % 3, t3p = (k - 1) % 3;
      bf16x8 xf;
      if (hasx)
        xf = cvt8(x + ((size_t)bb * kT + (k - 1)) * kI + xch * 32 + q * 8);
      bf16x8 ch[4];
      dataD<4>(h1b + ((k - 1) & 3) * kBH + (size_t)bb * kH + kh * 128 + q * 8,
               pat3(t3p), ch);
      f32x4 aR[4], aZ[4], aN[4];
#pragma unroll
      for (int m = 0; m < 4; ++m) { aR[m] = {0,0,0,0}; aZ[m] = {0,0,0,0}; aN[m] = {0,0,0,0}; }
#pragma unroll
      for (int m = 0; m < 4; ++m)
#pragma unroll
        for (int c = 0; c < 4; ++c) {
          aR[m] = mfma(whf[0][m][c], ch[c], aR[m]);
          aZ[m] = mfma(whf[1][m][c], ch[c], aZ[m]);
          aN[m] = mfma(whf[2][m][c], ch[c], aN[m]);
        }
      if (hasx) {
        f32x4 xN[4];
#pragma unroll
        for (int m = 0; m < 4; ++m) xN[m] = {0,0,0,0};
#pragma unroll
        for (int m = 0; m < 4; ++m) {
          aR[m] = mfma(aihf[0][m], xf, aR[m]);   // r,z: fold x into h-accum
          aZ[m] = mfma(aihf[1][m], xf, aZ[m]);
          xN[m] = mfma(aihf[2][m], xf, xN[m]);   // n_i must stay separate
        }
#pragma unroll
        for (int m = 0; m < 4; ++m)
#pragma unroll
          for (int r = 0; r < 4; ++r) redx[xch][m][lane][r] = xN[m][r];
      }
      if (kh != 0) {
#pragma unroll
        for (int m = 0; m < 4; ++m)
#pragma unroll
          for (int r = 0; r < 4; ++r) {
            red[kh - 1][0][m][lane][r] = aR[m][r];
            red[kh - 1][1][m][lane][r] = aZ[m][r];
            red[kh - 1][2][m][lane][r] = aN[m][r];
          }
      } else {
        throttle(ctl, thridx, thract, k, bound);   // h1 anti-dep
      }
      barrier_lds();
      if (kh == 0) {
#pragma unroll
        for (int m = 0; m < 4; ++m) {
          float hnew[4];
#pragma unroll
          for (int r = 0; r < 4; ++r) {
            float sR = aR[m][r] + red[0][0][m][lane][r] + red[1][0][m][lane][r] + red[2][0][m][lane][r];
            float sZ = aZ[m][r] + red[0][1][m][lane][r] + red[1][1][m][lane][r] + red[2][1][m][lane][r];
            float sN = aN[m][r] + red[0][2][m][lane][r] + red[1][2][m][lane][r] + red[2][2][m][lane][r];
            float sNi = redx[0][m][lane][r] + redx[1][m][lane][r];
            int uu = m * 16 + q * 4 + r;
            float rr = sigf(sR + sbias[0][uu]);
            float zz = sigf(sZ + sbias[1][uu]);
            float nn = tanhf_(sNi + sbias[2][uu] + rr * (sN + sbias[3][uu]));
            float h  = (1.0f - zz) * nn + zz * h1l[m][r];
            h1l[m][r] = h; hnew[r] = h;
          }
          st_h(h1b + (k & 3) * kBH + (size_t)bb * kH + U0 + m * 16 + q * 4, hnew, t3);
        }
      }
      barrier_lds();                      // guards red/redx reuse (no drain)
    }
  } else if (wg < 96) {
    // ---------------- layer 2 (combined K=1024 GEMM) ----------------
    const int j2 = wg - 32;
    const int ub2 = j2 >> 2, g = j2 & 3;
    const int U0 = ub2 * 32;
    const int bb = g * 16 + l15;
    const int kh = w;                     // 0,1: wih2 halves; 2,3: whh2 halves
    const float* src = (kh < 2) ? wih2 : whh2;
    const int koff = (kh & 1) * 256;      // K-offset within the 512-dim matrix
    bf16x8 whf[3][2][8];                  // 192 VGPR resident weights
#pragma unroll
    for (int gg = 0; gg < 3; ++gg)
#pragma unroll
      for (int m = 0; m < 2; ++m)
#pragma unroll
        for (int c = 0; c < 8; ++c)
          whf[gg][m][c] = cvt8(src + (size_t)(gg * kH + U0 + m * 16 + l15) * kH
                               + koff + c * 32 + q * 8);
    if (tid < 32) {                       // stage biases once
      int u = U0 + tid;
      sbias[0][tid] = bih2[u]          + bhh2[u];
      sbias[1][tid] = bih2[kH + u]     + bhh2[kH + u];
      sbias[2][tid] = bih2[2 * kH + u];
      sbias[3][tid] = bhh2[2 * kH + u];
    }
    float h2l[2][4];
#pragma unroll
    for (int m = 0; m < 2; ++m)
#pragma unroll
      for (int r = 0; r < 4; ++r) h2l[m][r] = 0.0f;
    __syncthreads();
    const bool upd = (kh == 0);
    int bound = 0;
    for (int k = 1; k <= kT; ++k) {
      const int t3 = k % 3, t3p = (k - 1) % 3;
      const u16* base; u32 pat;
      if (kh < 2) { base = h1b + (k & 3) * kBH;       pat = pat3(t3);  }
      else        { base = h2b + ((k - 1) & 3) * kBH; pat = pat3(t3p); }
      bf16x8 ch[8];
      dataD<8>(base + (size_t)bb * kH + koff + q * 8, pat, ch);
      f32x4 a[3][2];
#pragma unroll
      for (int gg = 0; gg < 3; ++gg)
#pragma unroll
        for (int m = 0; m < 2; ++m) a[gg][m] = {0,0,0,0};
#pragma unroll
      for (int m = 0; m < 2; ++m)
#pragma unroll
        for (int c = 0; c < 8; ++c) {
          a[0][m] = mfma(whf[0][m][c], ch[c], a[0][m]);
          a[1][m] = mfma(whf[1][m][c], ch[c], a[1][m]);
          a[2][m] = mfma(whf[2][m][c], ch[c], a[2][m]);
        }
      if (kh != 0) {
        const int s = kh - 1;             // kh1 -> gi-half2, kh2/3 -> gh halves
#pragma unroll
        for (int gg = 0; gg < 3; ++gg)
#pragma unroll
          for (int m = 0; m < 2; ++m)
#pragma unroll
            for (int r = 0; r < 4; ++r) red[s][gg][m][lane][r] = a[gg][m][r];
      } else {
        throttle(ctl, 64 + g, lane < 1, k, bound);   // h2 anti-dep (OUT)
      }
      barrier_lds();
      if (tid == 0) stflag(ctl, j2, k);   // all 4 waves fetch-verified tick k
      if (upd) {
#pragma unroll
        for (int m = 0; m < 2; ++m) {
          float hnew[4];
#pragma unroll
          for (int r = 0; r < 4; ++r) {
            float gi0 = a[0][m][r] + red[0][0][m][lane][r];
            float gi1 = a[1][m][r] + red[0][1][m][lane][r];
            float gi2 = a[2][m][r] + red[0][2][m][lane][r];
            float gh0 = red[1][0][m][lane][r] + red[2][0][m][lane][r];
            float gh1 = red[1][1][m][lane][r] + red[2][1][m][lane][r];
            float gh2 = red[1][2][m][lane][r] + red[2][2][m][lane][r];
            int uu = m * 16 + q * 4 + r;
            float rr = sigf(gi0 + gh0 + sbias[0][uu]);
            float zz = sigf(gi1 + gh1 + sbias[1][uu]);
            float nn = tanhf_(gi2 + sbias[2][uu] + rr * (gh2 + sbias[3][uu]));
            float h  = (1.0f - zz) * nn + zz * h2l[m][r];
            h2l[m][r] = h; hnew[r] = h;
          }
          st_h(h2b + (k & 3) * kBH + (size_t)bb * kH + U0 + m * 16 + q * 4, hnew, t3);
        }
      }
      barrier_lds();                      // guards red reuse (no drain)
    }
  } else {
    // ---------------- output head ----------------
    const int g3 = wg - 96;
    const int bb = g3 * 16 + l15;
    const int mat = w & 1, khh = w >> 1;  // matrix x K-half
    const float* wsel = mat ? wo2 : wo1;
    bf16x8 zf = {0,0,0,0,0,0,0,0};
    bf16x8 wof[2][8];
#pragma unroll
    for (int t = 0; t < 2; ++t)
#pragma unroll
      for (int c = 0; c < 8; ++c) {
        int row = t * 16 + l15;
        wof[t][c] = (row < kO) ? cvt8(wsel + (size_t)row * kH + khh * 256 + c * 32 + q * 8) : zf;
      }
    float bv1[2][4], bv2[2][4];
#pragma unroll
    for (int t = 0; t < 2; ++t)
#pragma unroll
      for (int r = 0; r < 4; ++r) {
        int o = t * 16 + q * 4 + r;
        bv1[t][r] = (o < kO) ? bo1[o] : 0.0f;
        bv2[t][r] = (o < kO) ? bo2[o] : 0.0f;
      }
    const bool fin = (mat == 0 && khh == 0);
    const u16* slab = mat ? h2b : h1b;
    for (int k = 1; k <= kT; ++k) {
      const u32 pat = pat3(k % 3);
      bf16x8 ch[8];
      dataD<8>(slab + (k & 3) * kBH + (size_t)bb * kH + khh * 256 + q * 8, pat, ch);
      f32x4 a0 = {0,0,0,0}, a1 = {0,0,0,0};
#pragma unroll
      for (int c = 0; c < 8; ++c) {
        a0 = mfma(wof[0][c], ch[c], a0);
        a1 = mfma(wof[1][c], ch[c], a1);
      }
      if (!fin) {
        const int s = mat * 2 + khh - 1;  // (0,1)->0 (1,0)->1 (1,1)->2
#pragma unroll
        for (int r = 0; r < 4; ++r) {
          red[s][0][0][lane][r] = a0[r];
          red[s][0][1][lane][r] = a1[r];
        }
      }
      barrier_lds();
      if (tid == 0) stflag(ctl, 64 + g3, k);   // h1[k] & h2[k] fetch-verified
      if (fin) {
#pragma unroll
        for (int t = 0; t < 2; ++t) {
          int o0 = t * 16 + q * 4;
          if (o0 < kO) {
            f32x4 av = (t == 0) ? a0 : a1;
            float4 ov;
            ov.x = tanhf_(av[0] + red[0][0][t][lane][0] + bv1[t][0]) +
                   tanhf_(red[1][0][t][lane][0] + red[2][0][t][lane][0] + bv2[t][0]);
            ov.y = tanhf_(av[1] + red[0][0][t][lane][1] + bv1[t][1]) +
                   tanhf_(red[1][0][t][lane][1] + red[2][0][t][lane][1] + bv2[t][1]);
            ov.z = tanhf_(av[2] + red[0][0][t][lane][2] + bv1[t][2]) +
                   tanhf_(red[1][0][t][lane][2] + red[2][0][t][lane][2] + bv2[t][2]);
            ov.w = tanhf_(av[3] + red[0][0][t][lane][3] + bv1[t][3]) +
                   tanhf_(red[1][0][t][lane][3] + red[2][0][t][lane][3] + bv2[t][3]);
            *reinterpret_cast<float4*>(out + ((size_t)bb * kT + (k - 1)) * kO + o0) = ov;
          }
        }
      }
      barrier_lds();                      // guards red reuse (no drain)
    }
  }
}

extern "C" void kernel_launch(void* const* d_in, const int* in_sizes, int n_in,
                              void* d_out, int out_size, void* d_ws, size_t ws_size,
                              hipStream_t stream) {
  (void)in_sizes; (void)n_in; (void)out_size; (void)ws_size;
  // zero h buffers + control page; invalid-tag init for buf 3 of h1 & h2
  hipMemsetAsync(d_ws, 0, kBarOff + 1024, stream);
  hipMemsetAsync((char*)d_ws + 3u * kBH * 2u, 0x01, kBH * 2u, stream);  // h1 buf3
  hipMemsetAsync((char*)d_ws + 7u * kBH * 2u, 0x01, kBH * 2u, stream);  // h2 buf3
  const float* x    = (const float*)d_in[0];
  const float* wih1 = (const float*)d_in[1];
  const float* whh1 = (const float*)d_in[2];
  const float* bih1 = (const float*)d_in[3];
  const float* bhh1 = (const float*)d_in[4];
  const float* wih2 = (const float*)d_in[5];
  const float* whh2 = (const float*)d_in[6];
  const float* bih2 = (const float*)d_in[7];
  const float* bhh2 = (const float*)d_in[8];
  const float* wo1  = (const float*)d_in[9];
  const float* bo1  = (const float*)d_in[10];
  const float* wo2  = (const float*)d_in[11];
  const float* bo2  = (const float*)d_in[12];
  float* out  = (float*)d_out;
  u16* hbuf   = (u16*)d_ws;
  int* ctl    = (int*)((char*)d_ws + kBarOff);
  stackgru<<<dim3(kNWG), dim3(256), 0, stream>>>(
      x, wih1, whh1, bih1, bhh1, wih2, whh2, bih2, bhh2,
      wo1, bo1, wo2, bo2, out, hbuf, ctl);
}

// Round 10
// 3553.149 us; speedup vs baseline: 2.6800x; 1.4599x over previous
//
#include <hip/hip_runtime.h>

typedef unsigned short u16;
typedef unsigned int u32;
typedef unsigned long long u64;
typedef __attribute__((ext_vector_type(8))) short bf16x8;   // 8 bf16 = 4 VGPRs
typedef __attribute__((ext_vector_type(4))) float f32x4;
typedef __attribute__((ext_vector_type(4))) u32 u32x4;

namespace {
constexpr int kT = 1024, kI = 64, kH = 512, kO = 24;
constexpr int kBH = 64 * kH;                  // 32768 elems per h buffer (bf16)
constexpr int kNWG = 100;                     // 32 L1 + 64 L2 + 4 OUT
// RING-8: h1 8 bufs @0, h2 8 bufs @512KB (buf = k&7), tags k mod 3 (unique
// mod 24; skew <= 8 via throttle). bufs 3,6 invalid-init (first tick b has
// b%3==0 == zero-init tag -- R8-class hazard).
constexpr unsigned kBarOff = 16u * (unsigned)kBH * 2u;  // 1048576 B
// ctl ints: [0..63] flagL2[j2] (j2 = ub2*4+g), [64..67] flagOUT[g]
}

__device__ __forceinline__ u16 f2bf(float f) {   // round-to-nearest-even
  union { float f; u32 u; } c; c.f = f;
  u32 u = c.u + 0x7FFFu + ((c.u >> 16) & 1u);
  return (u16)(u >> 16);
}
__device__ __forceinline__ float sigf(float x) { return 1.0f / (1.0f + __expf(-x)); }
__device__ __forceinline__ float tanhf_(float x) {
  float e = __expf(2.0f * x); return 1.0f - 2.0f / (e + 1.0f);  // safe at +-inf
}
__device__ __forceinline__ bf16x8 cvt8(const float* p) {  // fp32x8 -> bf16x8 (RNE)
  const float4 f0 = *reinterpret_cast<const float4*>(p);
  const float4 f1 = *reinterpret_cast<const float4*>(p + 4);
  bf16x8 r;
  r[0] = (short)f2bf(f0.x); r[1] = (short)f2bf(f0.y);
  r[2] = (short)f2bf(f0.z); r[3] = (short)f2bf(f0.w);
  r[4] = (short)f2bf(f1.x); r[5] = (short)f2bf(f1.y);
  r[6] = (short)f2bf(f1.z); r[7] = (short)f2bf(f1.w);
  return r;
}
__device__ __forceinline__ f32x4 mfma(bf16x8 a, bf16x8 b, f32x4 c) {
  return __builtin_amdgcn_mfma_f32_16x16x32_bf16(a, b, c, 0, 0, 0);
}
__device__ __forceinline__ int ldflag(const int* s, int i) {
  return __hip_atomic_load(&s[i], __ATOMIC_RELAXED, __HIP_MEMORY_SCOPE_AGENT);
}
__device__ __forceinline__ void stflag(int* s, int i, int v) {
  __hip_atomic_store(&s[i], v, __ATOMIC_RELAXED, __HIP_MEMORY_SCOPE_AGENT);
}
// PIPELINED agent fetch (R5-proven): all loads in one asm block, sc0 sc1,
// ONE vmcnt drain => ~1 round trip per handshake.
union V16 { u32x4 u; bf16x8 v; };
__device__ __forceinline__ void fetch4(const u16* p, bf16x8* ch) {
  u32x4 a, b, c, d;
  asm volatile(
    "global_load_dwordx4 %0, %4, off sc0 sc1\n\t"
    "global_load_dwordx4 %1, %4, off offset:64 sc0 sc1\n\t"
    "global_load_dwordx4 %2, %4, off offset:128 sc0 sc1\n\t"
    "global_load_dwordx4 %3, %4, off offset:192 sc0 sc1\n\t"
    "s_waitcnt vmcnt(0)"
    : "=&v"(a), "=&v"(b), "=&v"(c), "=&v"(d) : "v"(p) : "memory");
  V16 t;
  t.u = a; ch[0] = t.v;  t.u = b; ch[1] = t.v;
  t.u = c; ch[2] = t.v;  t.u = d; ch[3] = t.v;
}
__device__ __forceinline__ void fetch8(const u16* p, bf16x8* ch) {
  u32x4 a, b, c, d, e, f, g2, h;
  asm volatile(
    "global_load_dwordx4 %0, %8, off sc0 sc1\n\t"
    "global_load_dwordx4 %1, %8, off offset:64 sc0 sc1\n\t"
    "global_load_dwordx4 %2, %8, off offset:128 sc0 sc1\n\t"
    "global_load_dwordx4 %3, %8, off offset:192 sc0 sc1\n\t"
    "global_load_dwordx4 %4, %8, off offset:256 sc0 sc1\n\t"
    "global_load_dwordx4 %5, %8, off offset:320 sc0 sc1\n\t"
    "global_load_dwordx4 %6, %8, off offset:384 sc0 sc1\n\t"
    "global_load_dwordx4 %7, %8, off offset:448 sc0 sc1\n\t"
    "s_waitcnt vmcnt(0)"
    : "=&v"(a), "=&v"(b), "=&v"(c), "=&v"(d),
      "=&v"(e), "=&v"(f), "=&v"(g2), "=&v"(h) : "v"(p) : "memory");
  V16 t;
  t.u = a; ch[0] = t.v;  t.u = b;  ch[1] = t.v;
  t.u = c; ch[2] = t.v;  t.u = d;  ch[3] = t.v;
  t.u = e; ch[4] = t.v;  t.u = f;  ch[5] = t.v;
  t.u = g2; ch[6] = t.v; t.u = h;  ch[7] = t.v;
}
// tick tag (k mod 3) in LSBs of bf16 elems 0,1 of each 8B granule.
__device__ __forceinline__ u32 pat3(int t3) {
  return ((u32)t3 & 1u) | ((((u32)t3 >> 1) & 1u) << 16);
}
template<int N>
__device__ __forceinline__ bool tagsok(const bf16x8* ch, u32 pat) {
  bool ok = true;
#pragma unroll
  for (int c = 0; c < N; ++c) {
    union { bf16x8 v; u32 u[4]; } t; t.v = ch[c];
    ok = ok && ((t.u[0] & 0x10001u) == pat) && ((t.u[2] & 0x10001u) == pat);
  }
  return ok;
}
// tagged-data wait (R7-proven): phase 1 polls each lane's first 8B granule
// (cheap), phase 2 pipelined fetch + full tag verify (~1 iter).
template<int N>
__device__ __forceinline__ void dataD(const u16* p, u32 pat, bf16x8* ch) {
  int spins = 0;
  for (;;) {
    u64 g0 = __hip_atomic_load((const u64*)p, __ATOMIC_RELAXED, __HIP_MEMORY_SCOPE_AGENT);
    if (__all(((u32)g0 & 0x10001u) == pat)) break;
    if ((++spins & 3) == 3) __builtin_amdgcn_s_sleep(1);
  }
  spins = 0;
  for (;;) {
    if constexpr (N == 4) fetch4(p, ch); else fetch8(p, ch);
    if (__all(tagsok<N>(ch, pat))) break;
    if ((++spins & 7) == 7) __builtin_amdgcn_s_sleep(1);
  }
  __asm__ volatile("" ::: "memory");
}
// tagged h store: 4 bf16 + 2 tag bits, ONE agent-scope atomic 8B store
__device__ __forceinline__ void st_h(u16* p, const float* h, int t3) {
  u16 a = (u16)((f2bf(h[0]) & ~1u) | ((u32)t3 & 1u));
  u16 b = (u16)((f2bf(h[1]) & ~1u) | (((u32)t3 >> 1) & 1u));
  u64 v = (u64)a | ((u64)b << 16) | ((u64)f2bf(h[2]) << 32) | ((u64)f2bf(h[3]) << 48);
  __hip_atomic_store((u64*)p, v, __ATOMIC_RELAXED, __HIP_MEMORY_SCOPE_AGENT);
}
// RING-8 GRADED throttle (R9 post-mortem fix): ring-4's `>=k-3` check could
// never bank slack (consumer lag ~1-2 ticks => bound capped at k-3 => a
// serial flag RT EVERY tick on the critical wave). Ring-8 + graded bound
// banks the real consumer position => poll ~once per 7 ticks. Safety: tick
// k overwrites the buf holding k-8; gate flag >= k-7 (+1 margin, same
// transitive store-implies-read-done argument as ring-4).
__device__ __forceinline__ void throttle8(const int* f, int idx, bool act,
                                          int k, int& bound) {
  if (bound >= k - 7) return;
  for (;;) {
    int v = act ? ldflag(f, idx) : 0x7fffffff;
    if (__all(v >= k - 7)) {
      bound = __all(v >= k - 1) ? (k - 1) : (__all(v >= k - 4) ? (k - 4) : (k - 7));
      break;
    }
    __builtin_amdgcn_s_sleep(2);
  }
}

// FAT-WG roles (100 WGs x 256 thr; 4 batch-groups of 16) == R7 structure,
// with (a) ring-8 graded throttle and (b) activation DISTRIBUTED across
// waves: all 4 waves write partials to red[4][..]; after barrier, wave m
// sums+activates+stores unit-block m (L1: m=0..3, L2: m=0..1). Removes the
// two remaining serial per-tick costs (flag RT + one-wave activation).
//   wg  0..31 : L1. ub=wg>>2 (64-unit block), g=wg&3. 4 waves = K-quarters;
//               x-GEMM (K=64) on kh1/kh2, n-gate x-partial via LDS redx.
//   wg 32..95 : L2. ub2 (32-unit block), g. 4 waves = quarters of combined
//               K=1024: kh0,1 = wih2@h1[k]; kh2,3 = whh2@h2[k-1].
//   wg 96..99 : OUT. g3 group. 4 waves = mat x K-half. fin=mat0,kh0.
// flagL2[j2]/flagOUT[g] post after barrier 1 (all fetches tag-verified).
// MFMA 16x16x32: A=weights m=unit(l15), B=h n=batch(l15), C/D col=l15(batch),
// row=q*4+r(unit) -> activations lane-local.
__global__ __launch_bounds__(256, 1) void stackgru(
    const float* __restrict__ x,
    const float* __restrict__ wih1, const float* __restrict__ whh1,
    const float* __restrict__ bih1, const float* __restrict__ bhh1,
    const float* __restrict__ wih2, const float* __restrict__ whh2,
    const float* __restrict__ bih2, const float* __restrict__ bhh2,
    const float* __restrict__ wo1, const float* __restrict__ bo1,
    const float* __restrict__ wo2, const float* __restrict__ bo2,
    float* __restrict__ out, u16* __restrict__ hbuf, int* __restrict__ ctl)
{
  __shared__ float red[4][3][4][64][4];   // 48 KB: [kh][gate][m][lane][r]
  __shared__ float redx[2][4][64][4];     // 8 KB: x n-gate partials (L1)
  __shared__ float sbias[4][64];          // staged biases
  const int wg = blockIdx.x;
  const int tid = threadIdx.x;
  const int lane = tid & 63;
  const int w = tid >> 6;                 // wave 0..3
  const int l15 = lane & 15;
  const int q = lane >> 4;

  u16* h1b = hbuf;                        // 8 * kBH
  u16* h2b = hbuf + 8 * kBH;              // 8 * kBH

  if (wg < 32) {
    // ---------------- layer 1 ----------------
    const int ub = wg >> 2, g = wg & 3;
    const int U0 = ub * 64;
    const int bb = g * 16 + l15;
    const int kh = w;                     // K-quarter (0..3), 128 K each
    bf16x8 whf[3][4][4];                  // 192 VGPR resident w_hh1
#pragma unroll
    for (int gg = 0; gg < 3; ++gg)
#pragma unroll
      for (int m = 0; m < 4; ++m)
#pragma unroll
        for (int c = 0; c < 4; ++c)
          whf[gg][m][c] = cvt8(whh1 + (size_t)(gg * kH + U0 + m * 16 + l15) * kH
                               + (kh * 4 + c) * 32 + q * 8);
    const bool hasx = (kh == 1 || kh == 2);
    const int xch = kh - 1;               // x chunk 0/1 (K=64 total)
    bf16x8 aihf[3][4];                    // 48 VGPR (kh1/kh2 only)
    if (hasx)
#pragma unroll
      for (int gg = 0; gg < 3; ++gg)
#pragma unroll
        for (int m = 0; m < 4; ++m)
          aihf[gg][m] = cvt8(wih1 + (size_t)(gg * kH + U0 + m * 16 + l15) * kI
                             + xch * 32 + q * 8);
    if (tid < 64) {                       // stage biases once
      int u = U0 + tid;
      sbias[0][tid] = bih1[u]          + bhh1[u];
      sbias[1][tid] = bih1[kH + u]     + bhh1[kH + u];
      sbias[2][tid] = bih1[2 * kH + u];
      sbias[3][tid] = bhh1[2 * kH + u];
    }
    float h1l[4];                         // this wave's unit-block (m = w)
#pragma unroll
    for (int r = 0; r < 4; ++r) h1l[r] = 0.0f;
    __syncthreads();
    // throttle watch (kh0): lanes 0..15 = flagL2 of group, lane 16 = flagOUT
    const int thridx = (lane < 16) ? (lane * 4 + g) : (64 + g);
    const bool thract = (lane < 17);
    int bound = 0;
    for (int k = 1; k <= kT; ++k) {
      const int t3 = k % 3, t3p = (k - 1) % 3;
      bf16x8 xf;
      if (hasx)
        xf = cvt8(x + ((size_t)bb * kT + (k - 1)) * kI + xch * 32 + q * 8);
      bf16x8 ch[4];
      dataD<4>(h1b + ((k - 1) & 7) * kBH + (size_t)bb * kH + kh * 128 + q * 8,
               pat3(t3p), ch);
      f32x4 aR[4], aZ[4], aN[4];
#pragma unroll
      for (int m = 0; m < 4; ++m) { aR[m] = {0,0,0,0}; aZ[m] = {0,0,0,0}; aN[m] = {0,0,0,0}; }
#pragma unroll
      for (int m = 0; m < 4; ++m)
#pragma unroll
        for (int c = 0; c < 4; ++c) {
          aR[m] = mfma(whf[0][m][c], ch[c], aR[m]);
          aZ[m] = mfma(whf[1][m][c], ch[c], aZ[m]);
          aN[m] = mfma(whf[2][m][c], ch[c], aN[m]);
        }
      if (hasx) {
        f32x4 xN[4];
#pragma unroll
        for (int m = 0; m < 4; ++m) xN[m] = {0,0,0,0};
#pragma unroll
        for (int m = 0; m < 4; ++m) {
          aR[m] = mfma(aihf[0][m], xf, aR[m]);   // r,z: fold x into h-accum
          aZ[m] = mfma(aihf[1][m], xf, aZ[m]);
          xN[m] = mfma(aihf[2][m], xf, xN[m]);   // n_i must stay separate
        }
#pragma unroll
        for (int m = 0; m < 4; ++m)
#pragma unroll
          for (int r = 0; r < 4; ++r) redx[xch][m][lane][r] = xN[m][r];
      }
#pragma unroll
      for (int m = 0; m < 4; ++m)
#pragma unroll
        for (int r = 0; r < 4; ++r) {
          red[kh][0][m][lane][r] = aR[m][r];
          red[kh][1][m][lane][r] = aZ[m][r];
          red[kh][2][m][lane][r] = aN[m][r];
        }
      if (kh == 0) throttle8(ctl, thridx, thract, k, bound);   // h1 anti-dep
      __syncthreads();
      {                                   // distributed act: wave handles m=w
        float hnew[4];
#pragma unroll
        for (int r = 0; r < 4; ++r) {
          float sR = red[0][0][w][lane][r] + red[1][0][w][lane][r]
                   + red[2][0][w][lane][r] + red[3][0][w][lane][r];
          float sZ = red[0][1][w][lane][r] + red[1][1][w][lane][r]
                   + red[2][1][w][lane][r] + red[3][1][w][lane][r];
          float sN = red[0][2][w][lane][r] + red[1][2][w][lane][r]
                   + red[2][2][w][lane][r] + red[3][2][w][lane][r];
          float sNi = redx[0][w][lane][r] + redx[1][w][lane][r];
          int uu = w * 16 + q * 4 + r;
          float rr = sigf(sR + sbias[0][uu]);
          float zz = sigf(sZ + sbias[1][uu]);
          float nn = tanhf_(sNi + sbias[2][uu] + rr * (sN + sbias[3][uu]));
          float h  = (1.0f - zz) * nn + zz * h1l[r];
          h1l[r] = h; hnew[r] = h;
        }
        st_h(h1b + (k & 7) * kBH + (size_t)bb * kH + U0 + w * 16 + q * 4, hnew, t3);
      }
      __syncthreads();                    // guards red/redx reuse
    }
  } else if (wg < 96) {
    // ---------------- layer 2 (combined K=1024 GEMM) ----------------
    const int j2 = wg - 32;
    const int ub2 = j2 >> 2, g = j2 & 3;
    const int U0 = ub2 * 32;
    const int bb = g * 16 + l15;
    const int kh = w;                     // 0,1: wih2 halves; 2,3: whh2 halves
    const float* src = (kh < 2) ? wih2 : whh2;
    const int koff = (kh & 1) * 256;      // K-offset within the 512-dim matrix
    bf16x8 whf[3][2][8];                  // 192 VGPR resident weights
#pragma unroll
    for (int gg = 0; gg < 3; ++gg)
#pragma unroll
      for (int m = 0; m < 2; ++m)
#pragma unroll
        for (int c = 0; c < 8; ++c)
          whf[gg][m][c] = cvt8(src + (size_t)(gg * kH + U0 + m * 16 + l15) * kH
                               + koff + c * 32 + q * 8);
    if (tid < 32) {                       // stage biases once
      int u = U0 + tid;
      sbias[0][tid] = bih2[u]          + bhh2[u];
      sbias[1][tid] = bih2[kH + u]     + bhh2[kH + u];
      sbias[2][tid] = bih2[2 * kH + u];
      sbias[3][tid] = bhh2[2 * kH + u];
    }
    float h2l[4];                         // wave w<2 uses (unit-block m=w)
#pragma unroll
    for (int r = 0; r < 4; ++r) h2l[r] = 0.0f;
    __syncthreads();
    int bound = 0;
    for (int k = 1; k <= kT; ++k) {
      const int t3 = k % 3, t3p = (k - 1) % 3;
      const u16* base; u32 pat;
      if (kh < 2) { base = h1b + (k & 7) * kBH;       pat = pat3(t3);  }
      else        { base = h2b + ((k - 1) & 7) * kBH; pat = pat3(t3p); }
      bf16x8 ch[8];
      dataD<8>(base + (size_t)bb * kH + koff + q * 8, pat, ch);
      f32x4 a[3][2];
#pragma unroll
      for (int gg = 0; gg < 3; ++gg)
#pragma unroll
        for (int m = 0; m < 2; ++m) a[gg][m] = {0,0,0,0};
#pragma unroll
      for (int m = 0; m < 2; ++m)
#pragma unroll
        for (int c = 0; c < 8; ++c) {
          a[0][m] = mfma(whf[0][m][c], ch[c], a[0][m]);
          a[1][m] = mfma(whf[1][m][c], ch[c], a[1][m]);
          a[2][m] = mfma(whf[2][m][c], ch[c], a[2][m]);
        }
#pragma unroll
      for (int gg = 0; gg < 3; ++gg)
#pragma unroll
        for (int m = 0; m < 2; ++m)
#pragma unroll
          for (int r = 0; r < 4; ++r) red[kh][gg][m][lane][r] = a[gg][m][r];
      if (kh == 0) throttle8(ctl, 64 + g, lane < 1, k, bound);  // h2 anti-dep
      __syncthreads();
      if (tid == 0) stflag(ctl, j2, k);   // all 4 waves fetch-verified tick k
      if (w < 2) {                        // distributed act: wave m = w
        const int m = w;
        float hnew[4];
#pragma unroll
        for (int r = 0; r < 4; ++r) {
          float gi0 = red[0][0][m][lane][r] + red[1][0][m][lane][r];
          float gi1 = red[0][1][m][lane][r] + red[1][1][m][lane][r];
          float gi2 = red[0][2][m][lane][r] + red[1][2][m][lane][r];
          float gh0 = red[2][0][m][lane][r] + red[3][0][m][lane][r];
          float gh1 = red[2][1][m][lane][r] + red[3][1][m][lane][r];
          float gh2 = red[2][2][m][lane][r] + red[3][2][m][lane][r];
          int uu = m * 16 + q * 4 + r;
          float rr = sigf(gi0 + gh0 + sbias[0][uu]);
          float zz = sigf(gi1 + gh1 + sbias[1][uu]);
          float nn = tanhf_(gi2 + sbias[2][uu] + rr * (gh2 + sbias[3][uu]));
          float h  = (1.0f - zz) * nn + zz * h2l[r];
          h2l[r] = h; hnew[r] = h;
        }
        st_h(h2b + (k & 7) * kBH + (size_t)bb * kH + U0 + m * 16 + q * 4, hnew, t3);
      }
      __syncthreads();                    // guards red reuse
    }
  } else {
    // ---------------- output head ----------------
    const int g3 = wg - 96;
    const int bb = g3 * 16 + l15;
    const int mat = w & 1, khh = w >> 1;  // matrix x K-half
    const float* wsel = mat ? wo2 : wo1;
    bf16x8 zf = {0,0,0,0,0,0,0,0};
    bf16x8 wof[2][8];
#pragma unroll
    for (int t = 0; t < 2; ++t)
#pragma unroll
      for (int c = 0; c < 8; ++c) {
        int row = t * 16 + l15;
        wof[t][c] = (row < kO) ? cvt8(wsel + (size_t)row * kH + khh * 256 + c * 32 + q * 8) : zf;
      }
    float bv1[2][4], bv2[2][4];
#pragma unroll
    for (int t = 0; t < 2; ++t)
#pragma unroll
      for (int r = 0; r < 4; ++r) {
        int o = t * 16 + q * 4 + r;
        bv1[t][r] = (o < kO) ? bo1[o] : 0.0f;
        bv2[t][r] = (o < kO) ? bo2[o] : 0.0f;
      }
    const bool fin = (mat == 0 && khh == 0);
    const u16* slab = mat ? h2b : h1b;
    for (int k = 1; k <= kT; ++k) {
      const u32 pat = pat3(k % 3);
      bf16x8 ch[8];
      dataD<8>(slab + (k & 7) * kBH + (size_t)bb * kH + khh * 256 + q * 8, pat, ch);
      f32x4 a0 = {0,0,0,0}, a1 = {0,0,0,0};
#pragma unroll
      for (int c = 0; c < 8; ++c) {
        a0 = mfma(wof[0][c], ch[c], a0);
        a1 = mfma(wof[1][c], ch[c], a1);
      }
      if (!fin) {
        const int s = mat * 2 + khh - 1;  // (0,1)->0 (1,0)->1 (1,1)->2
#pragma unroll
        for (int r = 0; r < 4; ++r) {
          red[s][0][0][lane][r] = a0[r];
          red[s][0][1][lane][r] = a1[r];
        }
      }
      __syncthreads();
      if (tid == 0) stflag(ctl, 64 + g3, k);   // h1[k] & h2[k] fetch-verified
      if (fin) {
#pragma unroll
        for (int t = 0; t < 2; ++t) {
          int o0 = t * 16 + q * 4;
          if (o0 < kO) {
            f32x4 av = (t == 0) ? a0 : a1;
            float4 ov;
            ov.x = tanhf_(av[0] + red[0][0][t][lane][0] + bv1[t][0]) +
                   tanhf_(red[1][0][t][lane][0] + red[2][0][t][lane][0] + bv2[t][0]);
            ov.y = tanhf_(av[1] + red[0][0][t][lane][1] + bv1[t][1]) +
                   tanhf_(red[1][0][t][lane][1] + red[2][0][t][lane][1] + bv2[t][1]);
            ov.z = tanhf_(av[2] + red[0][0][t][lane][2] + bv1[t][2]) +
                   tanhf_(red[1][0][t][lane][2] + red[2][0][t][lane][2] + bv2[t][2]);
            ov.w = tanhf_(av[3] + red[0][0][t][lane][3] + bv1[t][3]) +
                   tanhf_(red[1][0][t][lane][3] + red[2][0][t][lane][3] + bv2[t][3]);
            *reinterpret_cast<float4*>(out + ((size_t)bb * kT + (k - 1)) * kO + o0) = ov;
          }
        }
      }
      __syncthreads();                    // guards red reuse
    }
  }
}

extern "C" void kernel_launch(void* const* d_in, const int* in_sizes, int n_in,
                              void* d_out, int out_size, void* d_ws, size_t ws_size,
                              hipStream_t stream) {
  (void)in_sizes; (void)n_in; (void)out_size; (void)ws_size;
  // zero h rings + control page; invalid-tag init for bufs 3,6 of h1 & h2
  // (first occupant tick b has b%3==0 == zero-init tag -- R8-class hazard)
  hipMemsetAsync(d_ws, 0, kBarOff + 1024, stream);
  hipMemsetAsync((char*)d_ws + 3u * kBH * 2u, 0x01, kBH * 2u, stream);              // h1 buf3
  hipMemsetAsync((char*)d_ws + 6u * kBH * 2u, 0x01, kBH * 2u, stream);              // h1 buf6
  hipMemsetAsync((char*)d_ws + (8u + 3u) * kBH * 2u, 0x01, kBH * 2u, stream);       // h2 buf3
  hipMemsetAsync((char*)d_ws + (8u + 6u) * kBH * 2u, 0x01, kBH * 2u, stream);       // h2 buf6
  const float* x    = (const float*)d_in[0];
  const float* wih1 = (const float*)d_in[1];
  const float* whh1 = (const float*)d_in[2];
  const float* bih1 = (const float*)d_in[3];
  const float* bhh1 = (const float*)d_in[4];
  const float* wih2 = (const float*)d_in[5];
  const float* whh2 = (const float*)d_in[6];
  const float* bih2 = (const float*)d_in[7];
  const float* bhh2 = (const float*)d_in[8];
  const float* wo1  = (const float*)d_in[9];
  const float* bo1  = (const float*)d_in[10];
  const float* wo2  = (const float*)d_in[11];
  const float* bo2  = (const float*)d_in[12];
  float* out  = (float*)d_out;
  u16* hbuf   = (u16*)d_ws;
  int* ctl    = (int*)((char*)d_ws + kBarOff);
  stackgru<<<dim3(kNWG), dim3(256), 0, stream>>>(
      x, wih1, whh1, bih1, bhh1, wih2, whh2, bih2, bhh2,
      wo1, bo1, wo2, bo2, out, hbuf, ctl);
}